// Round 2
// baseline (150.156 us; speedup 1.0000x reference)
//
#include <hip/hip_runtime.h>

#define B_ 32
#define N_ 1024
#define NEG 0.01f
#define QSC (1.4426950408889634f/32.0f)   // log2(e)/E folded into staged Wq/bq

using half8  = __attribute__((ext_vector_type(8))) _Float16;
using half4  = __attribute__((ext_vector_type(4))) _Float16;
using half2  = __attribute__((ext_vector_type(2))) _Float16;
using fp16x2 = __attribute__((ext_vector_type(2))) __fp16;
using floatx4 = __attribute__((ext_vector_type(4))) float;

#if defined(__has_builtin)
#if __has_builtin(__builtin_amdgcn_exp2f)
#define EXP2(x) __builtin_amdgcn_exp2f(x)
#endif
#endif
#ifndef EXP2
#define EXP2(x) exp2f(x)
#endif

#define MFMA32 __builtin_amdgcn_mfma_f32_16x16x32_f16
#define MFMA16 __builtin_amdgcn_mfma_f32_16x16x16f16

__device__ inline half2 pkcvt(float a, float b) {
    fp16x2 r = __builtin_amdgcn_cvt_pkrtz(a, b);
    return __builtin_bit_cast(half2, r);
}

__device__ inline half8 cvt8(float4 a, float4 b) {
    half2 p0 = pkcvt(a.x, a.y);
    half2 p1 = pkcvt(a.z, a.w);
    half2 p2 = pkcvt(b.x, b.y);
    half2 p3 = pkcvt(b.z, b.w);
    half8 h = { p0[0],p0[1], p1[0],p1[1], p2[0],p2[1], p3[0],p3[1] };
    return h;
}

// Single fused kernel, 512 threads = 8 waves, each wave owns 16 q rows.
// Same dataflow as the 98.6us baseline but 2 blocks/CU x 8 waves = 16 waves/CU
// (4/SIMD) instead of 8/CU. K/V tiles double-buffered; ONE barrier per K-tile.
struct __align__(16) Smem {
    _Float16 wsh[96*36];       // Wq(pre-scaled)/Wk/Wv for this group, stride 36
    float    bsh[96];
    _Float16 Kst[2][128*40];   // ping-pong K tile [kpos][e]
    _Float16 Vtst[2][32*136];  // ping-pong Vt tile [e][kpos]
    _Float16 qs[128*40];       // projected Q tile
    _Float16 xs[128*72];       // MLP input [q][ v(32) | attn(32) ] (rows wave-private)
    float bl1[32], bl10[32], bl11[32];
};  // 74.4 KB -> 2 blocks/CU

__global__ __launch_bounds__(512, 4) void fused_kernel(
    const float* __restrict__ x, const float* __restrict__ w_qkv, const float* __restrict__ b_qkv,
    const float* __restrict__ w_h1,  const float* __restrict__ b_h1,
    const float* __restrict__ w_h10, const float* __restrict__ b_h10,
    const float* __restrict__ w_h11, const float* __restrict__ b_h11,
    float* __restrict__ out)
{
    __shared__ Smem sm;
    int t = threadIdx.x;
    int bid = blockIdx.x;
    // XCD-affine remap: all 8 q-tile blocks of one bg land on the same XCD
    int xcd = bid & 7, j = bid >> 3;
    int bg = xcd*8 + (j >> 3);
    int qtile = j & 7;
    int b = bg >> 1, g = bg & 1;
    int qbase = qtile * 128;
    int lane = t & 63, w = t >> 6;
    int L15 = lane & 15, quad = lane >> 4;

    // ---- stage qkv weights (Q rows pre-scaled by QSC) + biases ----
    for (int idx = t; idx < 96*32; idx += 512) {
        int r = idx >> 5, c = idx & 31;
        float wv = w_qkv[(g*96 + r)*32 + c];
        sm.wsh[r*36 + c] = (_Float16)(r < 32 ? wv*QSC : wv);
    }
    if (t < 96) sm.bsh[t] = b_qkv[g*96 + t];
    if (t < 32) {
        sm.bl1[t]  = b_h1[g*32+t];
        sm.bl10[t] = b_h10[g*32+t];
        sm.bl11[t] = b_h11[g*32+t];
    }
    __syncthreads();

    // ---- K/V weight B-frags + bias scalars (seeds built at use) ----
    half8 bwk[2], bwv[2];
    float bkv[2], bvv[2];
    #pragma unroll
    for (int et = 0; et < 2; et++) {
        bwk[et] = *(const half8*)&sm.wsh[(32 + et*16 + L15)*36 + quad*8];
        bwv[et] = *(const half8*)&sm.wsh[(64 + et*16 + L15)*36 + quad*8];
        bkv[et] = sm.bsh[32 + et*16 + L15];
        bvv[et] = sm.bsh[64 + et*16 + L15];
    }

    // ---- project Q for own 16 rows -> qs ----
    {
        const float* p = x + ((size_t)b*N_ + qbase + w*16 + L15)*64 + g*32 + quad*8;
        half8 axq = cvt8(*(const float4*)p, *(const float4*)(p + 4));
        #pragma unroll
        for (int et = 0; et < 2; et++) {
            half8 bwq = *(const half8*)&sm.wsh[(et*16 + L15)*36 + quad*8];
            float bq = sm.bsh[et*16 + L15] * QSC;
            floatx4 cq = {bq,bq,bq,bq};
            floatx4 dq = MFMA32(axq, bwq, cq, 0,0,0);
            #pragma unroll
            for (int r = 0; r < 4; r++)
                sm.qs[(w*16 + quad*4 + r)*40 + et*16 + L15] = (_Float16)dq[r];
        }
    }
    __syncthreads();
    half8 bq0 = *(const half8*)&sm.qs[(w*16 + L15)*40 + quad*8];

    float4 xf0, xf1;
    auto prefetch = [&](int tile) {
        const float* p = x + ((size_t)b*N_ + tile*128 + w*16 + L15)*64 + g*32 + quad*8;
        xf0 = *(const float4*)p;
        xf1 = *(const float4*)(p + 4);
    };
    auto proj_tile = [&](int tile, int buf) {
        half8 ax = cvt8(xf0, xf1);
        floatx4 dK[2], dV[2];
        #pragma unroll
        for (int et = 0; et < 2; et++) {
            floatx4 ck = {bkv[et],bkv[et],bkv[et],bkv[et]};
            floatx4 cv = {bvv[et],bvv[et],bvv[et],bvv[et]};
            dK[et] = MFMA32(ax, bwk[et], ck, 0,0,0);
            dV[et] = MFMA32(ax, bwv[et], cv, 0,0,0);
        }
        int rb = w*16 + quad*4;
        #pragma unroll
        for (int et = 0; et < 2; et++) {
            half2 k01 = pkcvt(dK[et][0], dK[et][1]);
            half2 k23 = pkcvt(dK[et][2], dK[et][3]);
            sm.Kst[buf][(rb+0)*40 + et*16 + L15] = k01[0];
            sm.Kst[buf][(rb+1)*40 + et*16 + L15] = k01[1];
            sm.Kst[buf][(rb+2)*40 + et*16 + L15] = k23[0];
            sm.Kst[buf][(rb+3)*40 + et*16 + L15] = k23[1];
            half2 v01 = pkcvt(dV[et][0], dV[et][1]);
            half2 v23 = pkcvt(dV[et][2], dV[et][3]);
            half4 vh = { v01[0], v01[1], v23[0], v23[1] };
            *(half4*)&sm.Vtst[buf][(et*16 + L15)*136 + rb] = vh;
            if (tile == qtile) {   // own rows' V -> MLP input (uniform branch)
                #pragma unroll
                for (int r = 0; r < 4; r++)
                    sm.xs[(rb + r)*72 + et*16 + L15] = vh[r];
            }
        }
    };

    // ---- prologue: tile 0 ----
    prefetch(0);
    proj_tile(0, 0);
    __syncthreads();

    const floatx4 zz = {0.f,0.f,0.f,0.f};
    floatx4 o00 = zz, o01 = zz;
    float lsum0 = 0.f;

    for (int kt = 0; kt < 8; kt++) {
        int cur = kt & 1;
        if (kt < 7) prefetch(kt + 1);
        __builtin_amdgcn_s_setprio(1);
        #pragma unroll
        for (int m8 = 0; m8 < 8; m8++) {
            half8 ak = *(const half8*)&sm.Kst[cur][(m8*16 + L15)*40 + quad*8];
            floatx4 s0 = MFMA32(ak, bq0, zz, 0,0,0);
            float p00 = EXP2(s0.x), p01 = EXP2(s0.y), p02 = EXP2(s0.z), p03 = EXP2(s0.w);
            lsum0 += (p00+p01)+(p02+p03);
            half2 pa = pkcvt(p00, p01);
            half2 pb = pkcvt(p02, p03);
            half4 a0 = { pa[0], pa[1], pb[0], pb[1] };
            half4 bv0 = *(const half4*)&sm.Vtst[cur][      L15*136 + m8*16 + quad*4];
            half4 bv1 = *(const half4*)&sm.Vtst[cur][(16 + L15)*136 + m8*16 + quad*4];
            o00 = MFMA16(a0, bv0, o00, 0,0,0);
            o01 = MFMA16(a0, bv1, o01, 0,0,0);
        }
        __builtin_amdgcn_s_setprio(0);
        if (kt < 7) {
            proj_tile(kt + 1, 1 - cur);
            __syncthreads();
        }
    }

    // ---- softmax denominators: fold quads, fetch per-row inverse via shuffle ----
    lsum0 += __shfl_xor(lsum0, 16, 64);
    lsum0 += __shfl_xor(lsum0, 32, 64);
    float linv_own = 1.0f / lsum0;            // valid for q = w*16 + L15, all lanes
    float li0 = __shfl(linv_own, quad*4 + 0, 64);
    float li1 = __shfl(linv_own, quad*4 + 1, 64);
    float li2 = __shfl(linv_own, quad*4 + 2, 64);
    float li3 = __shfl(linv_own, quad*4 + 3, 64);

    // ---- attn part of xs (rows wave-private: no barrier needed) ----
    #pragma unroll
    for (int et = 0; et < 2; et++) {
        floatx4 ov = et ? o01 : o00;
        sm.xs[(w*16+quad*4+0)*72 + 32 + et*16 + L15] = (_Float16)(ov[0]*li0);
        sm.xs[(w*16+quad*4+1)*72 + 32 + et*16 + L15] = (_Float16)(ov[1]*li1);
        sm.xs[(w*16+quad*4+2)*72 + 32 + et*16 + L15] = (_Float16)(ov[2]*li2);
        sm.xs[(w*16+quad*4+3)*72 + 32 + et*16 + L15] = (_Float16)(ov[3]*li3);
    }

    // ---- MLP weight A-frags: A[m=o=mt*16+L15][k=i=quad*4+j] ----
    half4 a1f[2][4], a2f[2][2], a3f[2][2];
    #pragma unroll
    for (int mt = 0; mt < 2; mt++) {
        #pragma unroll
        for (int kt = 0; kt < 4; kt++) {
            float4 f = *(const float4*)(w_h1 + (size_t)(g*32+mt*16+L15)*64 + kt*16 + quad*4);
            half2 ha = pkcvt(f.x, f.y);
            half2 hb = pkcvt(f.z, f.w);
            half4 hh = { ha[0], ha[1], hb[0], hb[1] };
            a1f[mt][kt] = hh;
        }
        #pragma unroll
        for (int kt = 0; kt < 2; kt++) {
            float4 f = *(const float4*)(w_h10 + (size_t)(g*32+mt*16+L15)*32 + kt*16 + quad*4);
            half2 ha = pkcvt(f.x, f.y);
            half2 hb = pkcvt(f.z, f.w);
            half4 hh = { ha[0], ha[1], hb[0], hb[1] };
            a2f[mt][kt] = hh;
            float4 f2 = *(const float4*)(w_h11 + (size_t)(g*32+mt*16+L15)*32 + kt*16 + quad*4);
            half2 hc = pkcvt(f2.x, f2.y);
            half2 hd = pkcvt(f2.z, f2.w);
            half4 h2 = { hc[0], hc[1], hd[0], hd[1] };
            a3f[mt][kt] = h2;
        }
    }

    // ---- layer 1 (bias-seeded): D[o][q] over this wave's 16 q rows ----
    floatx4 d1[2];
    #pragma unroll
    for (int mt = 0; mt < 2; mt++) {
        float4 bb = *(const float4*)&sm.bl1[mt*16 + quad*4];
        d1[mt] = (floatx4){bb.x, bb.y, bb.z, bb.w};
    }
    #pragma unroll
    for (int kt = 0; kt < 4; kt++) {
        half4 b1 = *(const half4*)&sm.xs[(w*16 + L15)*72 + kt*16 + quad*4];
        d1[0] = MFMA16(a1f[0][kt], b1, d1[0], 0,0,0);
        d1[1] = MFMA16(a1f[1][kt], b1, d1[1], 0,0,0);
    }
    half4 h1b[2];
    #pragma unroll
    for (int mt = 0; mt < 2; mt++) {
        float v0 = d1[mt][0]; v0 = (v0>=0.f)?v0:NEG*v0;
        float v1 = d1[mt][1]; v1 = (v1>=0.f)?v1:NEG*v1;
        float v2 = d1[mt][2]; v2 = (v2>=0.f)?v2:NEG*v2;
        float v3 = d1[mt][3]; v3 = (v3>=0.f)?v3:NEG*v3;
        half2 ha = pkcvt(v0, v1);
        half2 hb = pkcvt(v2, v3);
        half4 hh = { ha[0], ha[1], hb[0], hb[1] };
        h1b[mt] = hh;
    }
    floatx4 d2[2];
    #pragma unroll
    for (int mt = 0; mt < 2; mt++) {
        float4 bb = *(const float4*)&sm.bl10[mt*16 + quad*4];
        d2[mt] = (floatx4){bb.x, bb.y, bb.z, bb.w};
        #pragma unroll
        for (int kt = 0; kt < 2; kt++)
            d2[mt] = MFMA16(a2f[mt][kt], h1b[kt], d2[mt], 0,0,0);
    }
    half4 h2b[2];
    #pragma unroll
    for (int mt = 0; mt < 2; mt++) {
        float v0 = d2[mt][0]; v0 = (v0>=0.f)?v0:NEG*v0;
        float v1 = d2[mt][1]; v1 = (v1>=0.f)?v1:NEG*v1;
        float v2 = d2[mt][2]; v2 = (v2>=0.f)?v2:NEG*v2;
        float v3 = d2[mt][3]; v3 = (v3>=0.f)?v3:NEG*v3;
        half2 ha = pkcvt(v0, v1);
        half2 hb = pkcvt(v2, v3);
        half4 hh = { ha[0], ha[1], hb[0], hb[1] };
        h2b[mt] = hh;
    }
    floatx4 d3[2];
    #pragma unroll
    for (int mt = 0; mt < 2; mt++) {
        float4 bb = *(const float4*)&sm.bl11[mt*16 + quad*4];
        d3[mt] = (floatx4){bb.x, bb.y, bb.z, bb.w};
        #pragma unroll
        for (int kt = 0; kt < 2; kt++)
            d3[mt] = MFMA16(a3f[mt][kt], h2b[kt], d3[mt], 0,0,0);
    }
    // store: lane holds out[q=qbase+w*16+L15][o=mt*16+quad*4+r] -> float4
    #pragma unroll
    for (int mt = 0; mt < 2; mt++) {
        float4 ov;
        ov.x = d3[mt][0]; ov.x = (ov.x>=0.f)?ov.x:NEG*ov.x;
        ov.y = d3[mt][1]; ov.y = (ov.y>=0.f)?ov.y:NEG*ov.y;
        ov.z = d3[mt][2]; ov.z = (ov.z>=0.f)?ov.z:NEG*ov.z;
        ov.w = d3[mt][3]; ov.w = (ov.w>=0.f)?ov.w:NEG*ov.w;
        *(float4*)(out + ((size_t)b*N_ + qbase + w*16 + L15)*64 + g*32 + mt*16 + quad*4) = ov;
    }
}

extern "C" void kernel_launch(void* const* d_in, const int* in_sizes, int n_in,
                              void* d_out, int out_size, void* d_ws, size_t ws_size,
                              hipStream_t stream) {
    const float* x_e   = (const float*)d_in[0];
    const float* w_qkv = (const float*)d_in[1];
    const float* b_qkv = (const float*)d_in[2];
    const float* w_h1  = (const float*)d_in[3];
    const float* b_h1  = (const float*)d_in[4];
    const float* w_h10 = (const float*)d_in[5];
    const float* b_h10 = (const float*)d_in[6];
    const float* w_h11 = (const float*)d_in[7];
    const float* b_h11 = (const float*)d_in[8];
    float* out = (float*)d_out;

    hipLaunchKernelGGL(fused_kernel, dim3(B_*2*8), dim3(512), 0, stream,
                       x_e, w_qkv, b_qkv, w_h1, b_h1, w_h10, b_h10, w_h11, b_h11, out);
}

// Round 3
// 119.193 us; speedup vs baseline: 1.2598x; 1.2598x over previous
//
#include <hip/hip_runtime.h>

#define B_ 32
#define N_ 1024
#define NEG 0.01f
#define QSC (1.4426950408889634f/32.0f)   // log2(e)/E folded into staged Wq/bq

using half8  = __attribute__((ext_vector_type(8))) _Float16;
using half4  = __attribute__((ext_vector_type(4))) _Float16;
using half2  = __attribute__((ext_vector_type(2))) _Float16;
using fp16x2 = __attribute__((ext_vector_type(2))) __fp16;
using floatx4 = __attribute__((ext_vector_type(4))) float;

#if defined(__has_builtin)
#if __has_builtin(__builtin_amdgcn_exp2f)
#define EXP2(x) __builtin_amdgcn_exp2f(x)
#endif
#endif
#ifndef EXP2
#define EXP2(x) exp2f(x)
#endif

#define MFMA32 __builtin_amdgcn_mfma_f32_16x16x32_f16
#define MFMA16 __builtin_amdgcn_mfma_f32_16x16x16f16

__device__ inline half2 pkcvt(float a, float b) {
    fp16x2 r = __builtin_amdgcn_cvt_pkrtz(a, b);
    return __builtin_bit_cast(half2, r);
}

__device__ inline half8 cvt8(float4 a, float4 b) {
    half2 p0 = pkcvt(a.x, a.y);
    half2 p1 = pkcvt(a.z, a.w);
    half2 p2 = pkcvt(b.x, b.y);
    half2 p3 = pkcvt(b.z, b.w);
    half8 h = { p0[0],p0[1], p1[0],p1[1], p2[0],p2[1], p3[0],p3[1] };
    return h;
}

// Single fused kernel, 512 threads = 8 waves, each wave owns 16 q rows.
// 2 blocks/CU x 8 waves = 16 waves/CU (4/SIMD).
// __launch_bounds__(512, 2): min 2 waves/EU -> VGPR cap 128 (NOT 4 -> 64,
// which spilled ~300MB of scratch per launch in the previous round).
struct __align__(16) Smem {
    _Float16 wsh[96*36];       // Wq(pre-scaled)/Wk/Wv for this group, stride 36
    float    bsh[96];
    _Float16 Kst[2][128*40];   // ping-pong K tile [kpos][e]
    _Float16 Vtst[2][32*136];  // ping-pong Vt tile [e][kpos]
    _Float16 qs[128*40];       // projected Q tile
    _Float16 xs[128*72];       // MLP input [q][ v(32) | attn(32) ] (rows wave-private)
    float bl1[32], bl10[32], bl11[32];
};  // 72.5 KB -> 2 blocks/CU

__global__ __launch_bounds__(512, 2) void fused_kernel(
    const float* __restrict__ x, const float* __restrict__ w_qkv, const float* __restrict__ b_qkv,
    const float* __restrict__ w_h1,  const float* __restrict__ b_h1,
    const float* __restrict__ w_h10, const float* __restrict__ b_h10,
    const float* __restrict__ w_h11, const float* __restrict__ b_h11,
    float* __restrict__ out)
{
    __shared__ Smem sm;
    int t = threadIdx.x;
    int bid = blockIdx.x;
    // XCD-affine remap: all 8 q-tile blocks of one bg land on the same XCD
    int xcd = bid & 7, j = bid >> 3;
    int bg = xcd*8 + (j >> 3);
    int qtile = j & 7;
    int b = bg >> 1, g = bg & 1;
    int qbase = qtile * 128;
    int lane = t & 63, w = t >> 6;
    int L15 = lane & 15, quad = lane >> 4;

    // ---- stage qkv weights (Q rows pre-scaled by QSC) + biases ----
    for (int idx = t; idx < 96*32; idx += 512) {
        int r = idx >> 5, c = idx & 31;
        float wv = w_qkv[(g*96 + r)*32 + c];
        sm.wsh[r*36 + c] = (_Float16)(r < 32 ? wv*QSC : wv);
    }
    if (t < 96) sm.bsh[t] = b_qkv[g*96 + t];
    if (t < 32) {
        sm.bl1[t]  = b_h1[g*32+t];
        sm.bl10[t] = b_h10[g*32+t];
        sm.bl11[t] = b_h11[g*32+t];
    }
    __syncthreads();

    // ---- K/V weight B-frags + bias scalars (seeds built at use) ----
    half8 bwk[2], bwv[2];
    float bkv[2], bvv[2];
    #pragma unroll
    for (int et = 0; et < 2; et++) {
        bwk[et] = *(const half8*)&sm.wsh[(32 + et*16 + L15)*36 + quad*8];
        bwv[et] = *(const half8*)&sm.wsh[(64 + et*16 + L15)*36 + quad*8];
        bkv[et] = sm.bsh[32 + et*16 + L15];
        bvv[et] = sm.bsh[64 + et*16 + L15];
    }

    // ---- project Q for own 16 rows -> qs ----
    {
        const float* p = x + ((size_t)b*N_ + qbase + w*16 + L15)*64 + g*32 + quad*8;
        half8 axq = cvt8(*(const float4*)p, *(const float4*)(p + 4));
        #pragma unroll
        for (int et = 0; et < 2; et++) {
            half8 bwq = *(const half8*)&sm.wsh[(et*16 + L15)*36 + quad*8];
            float bq = sm.bsh[et*16 + L15] * QSC;
            floatx4 cq = {bq,bq,bq,bq};
            floatx4 dq = MFMA32(axq, bwq, cq, 0,0,0);
            #pragma unroll
            for (int r = 0; r < 4; r++)
                sm.qs[(w*16 + quad*4 + r)*40 + et*16 + L15] = (_Float16)dq[r];
        }
    }
    __syncthreads();
    half8 bq0 = *(const half8*)&sm.qs[(w*16 + L15)*40 + quad*8];

    float4 xf0, xf1;
    auto prefetch = [&](int tile) {
        const float* p = x + ((size_t)b*N_ + tile*128 + w*16 + L15)*64 + g*32 + quad*8;
        xf0 = *(const float4*)p;
        xf1 = *(const float4*)(p + 4);
    };
    auto proj_tile = [&](int tile, int buf) {
        half8 ax = cvt8(xf0, xf1);
        floatx4 dK[2], dV[2];
        #pragma unroll
        for (int et = 0; et < 2; et++) {
            floatx4 ck = {bkv[et],bkv[et],bkv[et],bkv[et]};
            floatx4 cv = {bvv[et],bvv[et],bvv[et],bvv[et]};
            dK[et] = MFMA32(ax, bwk[et], ck, 0,0,0);
            dV[et] = MFMA32(ax, bwv[et], cv, 0,0,0);
        }
        int rb = w*16 + quad*4;
        #pragma unroll
        for (int et = 0; et < 2; et++) {
            half2 k01 = pkcvt(dK[et][0], dK[et][1]);
            half2 k23 = pkcvt(dK[et][2], dK[et][3]);
            sm.Kst[buf][(rb+0)*40 + et*16 + L15] = k01[0];
            sm.Kst[buf][(rb+1)*40 + et*16 + L15] = k01[1];
            sm.Kst[buf][(rb+2)*40 + et*16 + L15] = k23[0];
            sm.Kst[buf][(rb+3)*40 + et*16 + L15] = k23[1];
            half2 v01 = pkcvt(dV[et][0], dV[et][1]);
            half2 v23 = pkcvt(dV[et][2], dV[et][3]);
            half4 vh = { v01[0], v01[1], v23[0], v23[1] };
            *(half4*)&sm.Vtst[buf][(et*16 + L15)*136 + rb] = vh;
            if (tile == qtile) {   // own rows' V -> MLP input (uniform branch)
                #pragma unroll
                for (int r = 0; r < 4; r++)
                    sm.xs[(rb + r)*72 + et*16 + L15] = vh[r];
            }
        }
    };

    // ---- prologue: tile 0 ----
    prefetch(0);
    proj_tile(0, 0);
    __syncthreads();

    const floatx4 zz = {0.f,0.f,0.f,0.f};
    floatx4 o00 = zz, o01 = zz;
    float lsum0 = 0.f;

    for (int kt = 0; kt < 8; kt++) {
        int cur = kt & 1;
        if (kt < 7) prefetch(kt + 1);
        __builtin_amdgcn_s_setprio(1);
        #pragma unroll
        for (int m8 = 0; m8 < 8; m8++) {
            half8 ak = *(const half8*)&sm.Kst[cur][(m8*16 + L15)*40 + quad*8];
            floatx4 s0 = MFMA32(ak, bq0, zz, 0,0,0);
            float p00 = EXP2(s0.x), p01 = EXP2(s0.y), p02 = EXP2(s0.z), p03 = EXP2(s0.w);
            lsum0 += (p00+p01)+(p02+p03);
            half2 pa = pkcvt(p00, p01);
            half2 pb = pkcvt(p02, p03);
            half4 a0 = { pa[0], pa[1], pb[0], pb[1] };
            half4 bv0 = *(const half4*)&sm.Vtst[cur][      L15*136 + m8*16 + quad*4];
            half4 bv1 = *(const half4*)&sm.Vtst[cur][(16 + L15)*136 + m8*16 + quad*4];
            o00 = MFMA16(a0, bv0, o00, 0,0,0);
            o01 = MFMA16(a0, bv1, o01, 0,0,0);
        }
        __builtin_amdgcn_s_setprio(0);
        if (kt < 7) {
            proj_tile(kt + 1, 1 - cur);
            __syncthreads();
        }
    }

    // ---- softmax denominators: fold quads, fetch per-row inverse via shuffle ----
    lsum0 += __shfl_xor(lsum0, 16, 64);
    lsum0 += __shfl_xor(lsum0, 32, 64);
    float linv_own = 1.0f / lsum0;            // valid for q = w*16 + L15, all lanes
    float li0 = __shfl(linv_own, quad*4 + 0, 64);
    float li1 = __shfl(linv_own, quad*4 + 1, 64);
    float li2 = __shfl(linv_own, quad*4 + 2, 64);
    float li3 = __shfl(linv_own, quad*4 + 3, 64);

    // ---- attn part of xs (rows wave-private: no barrier needed) ----
    #pragma unroll
    for (int et = 0; et < 2; et++) {
        floatx4 ov = et ? o01 : o00;
        sm.xs[(w*16+quad*4+0)*72 + 32 + et*16 + L15] = (_Float16)(ov[0]*li0);
        sm.xs[(w*16+quad*4+1)*72 + 32 + et*16 + L15] = (_Float16)(ov[1]*li1);
        sm.xs[(w*16+quad*4+2)*72 + 32 + et*16 + L15] = (_Float16)(ov[2]*li2);
        sm.xs[(w*16+quad*4+3)*72 + 32 + et*16 + L15] = (_Float16)(ov[3]*li3);
    }

    // ---- MLP weight A-frags: A[m=o=mt*16+L15][k=i=quad*4+j] ----
    half4 a1f[2][4], a2f[2][2], a3f[2][2];
    #pragma unroll
    for (int mt = 0; mt < 2; mt++) {
        #pragma unroll
        for (int kt = 0; kt < 4; kt++) {
            float4 f = *(const float4*)(w_h1 + (size_t)(g*32+mt*16+L15)*64 + kt*16 + quad*4);
            half2 ha = pkcvt(f.x, f.y);
            half2 hb = pkcvt(f.z, f.w);
            half4 hh = { ha[0], ha[1], hb[0], hb[1] };
            a1f[mt][kt] = hh;
        }
        #pragma unroll
        for (int kt = 0; kt < 2; kt++) {
            float4 f = *(const float4*)(w_h10 + (size_t)(g*32+mt*16+L15)*32 + kt*16 + quad*4);
            half2 ha = pkcvt(f.x, f.y);
            half2 hb = pkcvt(f.z, f.w);
            half4 hh = { ha[0], ha[1], hb[0], hb[1] };
            a2f[mt][kt] = hh;
            float4 f2 = *(const float4*)(w_h11 + (size_t)(g*32+mt*16+L15)*32 + kt*16 + quad*4);
            half2 hc = pkcvt(f2.x, f2.y);
            half2 hd = pkcvt(f2.z, f2.w);
            half4 h2 = { hc[0], hc[1], hd[0], hd[1] };
            a3f[mt][kt] = h2;
        }
    }

    // ---- layer 1 (bias-seeded): D[o][q] over this wave's 16 q rows ----
    floatx4 d1[2];
    #pragma unroll
    for (int mt = 0; mt < 2; mt++) {
        float4 bb = *(const float4*)&sm.bl1[mt*16 + quad*4];
        d1[mt] = (floatx4){bb.x, bb.y, bb.z, bb.w};
    }
    #pragma unroll
    for (int kt = 0; kt < 4; kt++) {
        half4 b1 = *(const half4*)&sm.xs[(w*16 + L15)*72 + kt*16 + quad*4];
        d1[0] = MFMA16(a1f[0][kt], b1, d1[0], 0,0,0);
        d1[1] = MFMA16(a1f[1][kt], b1, d1[1], 0,0,0);
    }
    half4 h1b[2];
    #pragma unroll
    for (int mt = 0; mt < 2; mt++) {
        float v0 = d1[mt][0]; v0 = (v0>=0.f)?v0:NEG*v0;
        float v1 = d1[mt][1]; v1 = (v1>=0.f)?v1:NEG*v1;
        float v2 = d1[mt][2]; v2 = (v2>=0.f)?v2:NEG*v2;
        float v3 = d1[mt][3]; v3 = (v3>=0.f)?v3:NEG*v3;
        half2 ha = pkcvt(v0, v1);
        half2 hb = pkcvt(v2, v3);
        half4 hh = { ha[0], ha[1], hb[0], hb[1] };
        h1b[mt] = hh;
    }
    floatx4 d2[2];
    #pragma unroll
    for (int mt = 0; mt < 2; mt++) {
        float4 bb = *(const float4*)&sm.bl10[mt*16 + quad*4];
        d2[mt] = (floatx4){bb.x, bb.y, bb.z, bb.w};
        #pragma unroll
        for (int kt = 0; kt < 2; kt++)
            d2[mt] = MFMA16(a2f[mt][kt], h1b[kt], d2[mt], 0,0,0);
    }
    half4 h2b[2];
    #pragma unroll
    for (int mt = 0; mt < 2; mt++) {
        float v0 = d2[mt][0]; v0 = (v0>=0.f)?v0:NEG*v0;
        float v1 = d2[mt][1]; v1 = (v1>=0.f)?v1:NEG*v1;
        float v2 = d2[mt][2]; v2 = (v2>=0.f)?v2:NEG*v2;
        float v3 = d2[mt][3]; v3 = (v3>=0.f)?v3:NEG*v3;
        half2 ha = pkcvt(v0, v1);
        half2 hb = pkcvt(v2, v3);
        half4 hh = { ha[0], ha[1], hb[0], hb[1] };
        h2b[mt] = hh;
    }
    floatx4 d3[2];
    #pragma unroll
    for (int mt = 0; mt < 2; mt++) {
        float4 bb = *(const float4*)&sm.bl11[mt*16 + quad*4];
        d3[mt] = (floatx4){bb.x, bb.y, bb.z, bb.w};
        #pragma unroll
        for (int kt = 0; kt < 2; kt++)
            d3[mt] = MFMA16(a3f[mt][kt], h2b[kt], d3[mt], 0,0,0);
    }
    // store: lane holds out[q=qbase+w*16+L15][o=mt*16+quad*4+r] -> float4
    #pragma unroll
    for (int mt = 0; mt < 2; mt++) {
        float4 ov;
        ov.x = d3[mt][0]; ov.x = (ov.x>=0.f)?ov.x:NEG*ov.x;
        ov.y = d3[mt][1]; ov.y = (ov.y>=0.f)?ov.y:NEG*ov.y;
        ov.z = d3[mt][2]; ov.z = (ov.z>=0.f)?ov.z:NEG*ov.z;
        ov.w = d3[mt][3]; ov.w = (ov.w>=0.f)?ov.w:NEG*ov.w;
        *(float4*)(out + ((size_t)b*N_ + qbase + w*16 + L15)*64 + g*32 + mt*16 + quad*4) = ov;
    }
}

extern "C" void kernel_launch(void* const* d_in, const int* in_sizes, int n_in,
                              void* d_out, int out_size, void* d_ws, size_t ws_size,
                              hipStream_t stream) {
    const float* x_e   = (const float*)d_in[0];
    const float* w_qkv = (const float*)d_in[1];
    const float* b_qkv = (const float*)d_in[2];
    const float* w_h1  = (const float*)d_in[3];
    const float* b_h1  = (const float*)d_in[4];
    const float* w_h10 = (const float*)d_in[5];
    const float* b_h10 = (const float*)d_in[6];
    const float* w_h11 = (const float*)d_in[7];
    const float* b_h11 = (const float*)d_in[8];
    float* out = (float*)d_out;

    hipLaunchKernelGGL(fused_kernel, dim3(B_*2*8), dim3(512), 0, stream,
                       x_e, w_qkv, b_qkv, w_h1, b_h1, w_h10, b_h10, w_h11, b_h11, out);
}

// Round 4
// 97.856 us; speedup vs baseline: 1.5345x; 1.2180x over previous
//
#include <hip/hip_runtime.h>

#define B_ 32
#define N_ 1024
#define NEG 0.01f
#define QSC (1.4426950408889634f/32.0f)   // log2(e)/E folded into staged Wq/bq

using half8  = __attribute__((ext_vector_type(8))) _Float16;
using half4  = __attribute__((ext_vector_type(4))) _Float16;
using half2  = __attribute__((ext_vector_type(2))) _Float16;
using fp16x2 = __attribute__((ext_vector_type(2))) __fp16;
using floatx4 = __attribute__((ext_vector_type(4))) float;

#if defined(__has_builtin)
#if __has_builtin(__builtin_amdgcn_exp2f)
#define EXP2(x) __builtin_amdgcn_exp2f(x)
#endif
#endif
#ifndef EXP2
#define EXP2(x) exp2f(x)
#endif

#define MFMA32 __builtin_amdgcn_mfma_f32_16x16x32_f16
#define MFMA16 __builtin_amdgcn_mfma_f32_16x16x16f16

__device__ inline half2 pkcvt(float a, float b) {
    fp16x2 r = __builtin_amdgcn_cvt_pkrtz(a, b);
    return __builtin_bit_cast(half2, r);
}

__device__ inline half8 cvt8(float4 a, float4 b) {
    half2 p0 = pkcvt(a.x, a.y);
    half2 p1 = pkcvt(a.z, a.w);
    half2 p2 = pkcvt(b.x, b.y);
    half2 p3 = pkcvt(b.z, b.w);
    half8 h = { p0[0],p0[1], p1[0],p1[1], p2[0],p2[1], p3[0],p3[1] };
    return h;
}

// One fused kernel (round-0 structure: 256 thr = 4 waves, 32 q-rows/wave,
// cap-256 VGPR -> no spill) + verified grafts: XCD-affine remap, setprio
// around attention MFMAs, shuffle-based linv epilogue (2 barriers removed).
struct __align__(16) Smem {
    _Float16 wsh[96*36];       // Wq(pre-scaled)/Wk/Wv for this group, stride 36
    float    bsh[96];
    _Float16 Kst[2][128*40];   // ping-pong K tile [kpos][e]
    _Float16 Vtst[2][32*136];  // ping-pong Vt tile [e][kpos]
    union {
        _Float16 qs[128*40];   // projected Q tile (dead after bq frags read)
        _Float16 xs[128*72];   // MLP input [q][ v(32) | attn(32) ]
    } u;
    float bl1[32], bl10[32], bl11[32];
};  // 62.5 KB -> 2 blocks/CU

__global__ __launch_bounds__(256, 2) void fused_kernel(
    const float* __restrict__ x, const float* __restrict__ w_qkv, const float* __restrict__ b_qkv,
    const float* __restrict__ w_h1,  const float* __restrict__ b_h1,
    const float* __restrict__ w_h10, const float* __restrict__ b_h10,
    const float* __restrict__ w_h11, const float* __restrict__ b_h11,
    float* __restrict__ out)
{
    __shared__ Smem sm;
    int t = threadIdx.x;
    int bid = blockIdx.x;
    // XCD-affine remap: all 8 q-tile blocks of one bg land on the same XCD
    int xcd = bid & 7, j = bid >> 3;
    int bg = xcd*8 + (j >> 3);
    int qtile = j & 7;
    int b = bg >> 1, g = bg & 1;
    int qbase = qtile * 128;
    int lane = t & 63, w = t >> 6;
    int L15 = lane & 15, quad = lane >> 4;

    // ---- stage qkv weights (Q rows pre-scaled by QSC) + biases ----
    for (int idx = t; idx < 96*32; idx += 256) {
        int r = idx >> 5, c = idx & 31;
        float wv = w_qkv[(g*96 + r)*32 + c];
        sm.wsh[r*36 + c] = (_Float16)(r < 32 ? wv*QSC : wv);
    }
    if (t < 96) sm.bsh[t] = b_qkv[g*96 + t];
    if (t < 32) {
        sm.bl1[t]  = b_h1[g*32+t];
        sm.bl10[t] = b_h10[g*32+t];
        sm.bl11[t] = b_h11[g*32+t];
    }
    __syncthreads();

    // ---- weight B-frags: B[k=i=quad*8+j][n=e=et*16+L15] = W[e][i]; bias C-seeds ----
    half8 bwq[2], bwk[2], bwv[2];
    floatx4 cq[2], ck[2], cv[2];
    #pragma unroll
    for (int et = 0; et < 2; et++) {
        bwq[et] = *(const half8*)&sm.wsh[(     et*16 + L15)*36 + quad*8];
        bwk[et] = *(const half8*)&sm.wsh[(32 + et*16 + L15)*36 + quad*8];
        bwv[et] = *(const half8*)&sm.wsh[(64 + et*16 + L15)*36 + quad*8];
        float bq = sm.bsh[     et*16 + L15] * QSC;
        float bk = sm.bsh[32 + et*16 + L15];
        float bv = sm.bsh[64 + et*16 + L15];
        cq[et] = (floatx4){bq,bq,bq,bq};
        ck[et] = (floatx4){bk,bk,bk,bk};
        cv[et] = (floatx4){bv,bv,bv,bv};
    }

    // ---- project Q for own 32 rows/wave -> qs ----
    {
        floatx4 dq[2][2];
        #pragma unroll
        for (int mt = 0; mt < 2; mt++) {
            const float* p = x + ((size_t)b*N_ + qbase + w*32 + mt*16 + L15)*64 + g*32 + quad*8;
            half8 axq = cvt8(*(const float4*)p, *(const float4*)(p + 4));
            dq[mt][0] = MFMA32(axq, bwq[0], cq[0], 0,0,0);
            dq[mt][1] = MFMA32(axq, bwq[1], cq[1], 0,0,0);
        }
        #pragma unroll
        for (int mt = 0; mt < 2; mt++)
            #pragma unroll
            for (int et = 0; et < 2; et++)
                #pragma unroll
                for (int r = 0; r < 4; r++)
                    sm.u.qs[(w*32 + mt*16 + quad*4 + r)*40 + et*16 + L15] =
                        (_Float16)dq[mt][et][r];
    }
    __syncthreads();
    half8 bq0 = *(const half8*)&sm.u.qs[(w*32 +      L15)*40 + quad*8];
    half8 bq1 = *(const half8*)&sm.u.qs[(w*32 + 16 + L15)*40 + quad*8];
    __syncthreads();   // qs (union w/ xs) fully read by ALL waves before any xs write

    float4 xf0[2], xf1[2];
    auto prefetch = [&](int tile) {
        #pragma unroll
        for (int mt = 0; mt < 2; mt++) {
            const float* p = x + ((size_t)b*N_ + tile*128 + w*32 + mt*16 + L15)*64 + g*32 + quad*8;
            xf0[mt] = *(const float4*)p;
            xf1[mt] = *(const float4*)(p + 4);
        }
    };
    auto proj_tile = [&](int tile, int buf) {
        floatx4 dK[2][2], dV[2][2];
        #pragma unroll
        for (int mt = 0; mt < 2; mt++) {
            half8 axk = cvt8(xf0[mt], xf1[mt]);
            dK[mt][0] = MFMA32(axk, bwk[0], ck[0], 0,0,0);
            dK[mt][1] = MFMA32(axk, bwk[1], ck[1], 0,0,0);
            dV[mt][0] = MFMA32(axk, bwv[0], cv[0], 0,0,0);
            dV[mt][1] = MFMA32(axk, bwv[1], cv[1], 0,0,0);
        }
        #pragma unroll
        for (int mt = 0; mt < 2; mt++) {
            int rb = w*32 + mt*16 + quad*4;
            #pragma unroll
            for (int et = 0; et < 2; et++) {
                half2 k01 = pkcvt(dK[mt][et][0], dK[mt][et][1]);
                half2 k23 = pkcvt(dK[mt][et][2], dK[mt][et][3]);
                half2 v01 = pkcvt(dV[mt][et][0], dV[mt][et][1]);
                half2 v23 = pkcvt(dV[mt][et][2], dV[mt][et][3]);
                half4 vh = { v01[0], v01[1], v23[0], v23[1] };
                sm.Kst[buf][(rb+0)*40 + et*16 + L15] = k01[0];
                sm.Kst[buf][(rb+1)*40 + et*16 + L15] = k01[1];
                sm.Kst[buf][(rb+2)*40 + et*16 + L15] = k23[0];
                sm.Kst[buf][(rb+3)*40 + et*16 + L15] = k23[1];
                *(half4*)&sm.Vtst[buf][(et*16 + L15)*136 + rb] = vh;
                if (tile == qtile) {   // own rows' V -> MLP input (uniform branch)
                    #pragma unroll
                    for (int r = 0; r < 4; r++)
                        sm.u.xs[(rb + r)*72 + et*16 + L15] = vh[r];
                }
            }
        }
    };

    // ---- prologue: tile 0 ----
    prefetch(0);
    proj_tile(0, 0);
    __syncthreads();

    floatx4 o00 = {0.f,0.f,0.f,0.f}, o01 = o00, o10 = o00, o11 = o00;
    float lsum0 = 0.f, lsum1 = 0.f;

    for (int kt = 0; kt < 8; kt++) {
        int cur = kt & 1;
        if (kt < 7) prefetch(kt + 1);
        // attention on tile kt (buf cur) — hides prefetch latency
        __builtin_amdgcn_s_setprio(1);
        #pragma unroll
        for (int mt8 = 0; mt8 < 8; mt8++) {
            half8 ak = *(const half8*)&sm.Kst[cur][(mt8*16 + L15)*40 + quad*8];
            floatx4 zz = {0.f,0.f,0.f,0.f};
            floatx4 s0 = MFMA32(ak, bq0, zz, 0,0,0);
            floatx4 s1 = MFMA32(ak, bq1, zz, 0,0,0);
            float p00 = EXP2(s0.x), p01 = EXP2(s0.y), p02 = EXP2(s0.z), p03 = EXP2(s0.w);
            float p10 = EXP2(s1.x), p11 = EXP2(s1.y), p12 = EXP2(s1.z), p13 = EXP2(s1.w);
            lsum0 += (p00+p01)+(p02+p03);
            lsum1 += (p10+p11)+(p12+p13);
            half2 pa = pkcvt(p00, p01);
            half2 pb = pkcvt(p02, p03);
            half2 pc = pkcvt(p10, p11);
            half2 pd = pkcvt(p12, p13);
            half4 a0 = { pa[0], pa[1], pb[0], pb[1] };
            half4 a1 = { pc[0], pc[1], pd[0], pd[1] };
            half4 bv0 = *(const half4*)&sm.Vtst[cur][      L15*136 + mt8*16 + quad*4];
            half4 bv1 = *(const half4*)&sm.Vtst[cur][(16 + L15)*136 + mt8*16 + quad*4];
            o00 = MFMA16(a0, bv0, o00, 0,0,0);
            o01 = MFMA16(a0, bv1, o01, 0,0,0);
            o10 = MFMA16(a1, bv0, o10, 0,0,0);
            o11 = MFMA16(a1, bv1, o11, 0,0,0);
        }
        __builtin_amdgcn_s_setprio(0);
        // project tile kt+1 into the other buffer (no wait on attend reads)
        if (kt < 7) {
            proj_tile(kt + 1, 1 - cur);
            __syncthreads();
        }
    }

    // ---- softmax denominators: fold quads, per-row inverses via shuffles ----
    lsum0 += __shfl_xor(lsum0, 16, 64); lsum0 += __shfl_xor(lsum0, 32, 64);
    lsum1 += __shfl_xor(lsum1, 16, 64); lsum1 += __shfl_xor(lsum1, 32, 64);
    float inv0 = 1.0f / lsum0;   // row w*32 + L15 (all lanes)
    float inv1 = 1.0f / lsum1;   // row w*32 + 16 + L15
    float li[2][4];
    #pragma unroll
    for (int r = 0; r < 4; r++) {
        li[0][r] = __shfl(inv0, quad*4 + r, 64);
        li[1][r] = __shfl(inv1, quad*4 + r, 64);
    }

    // ---- attn part of xs: rows are wave-private -> no barriers needed ----
    {
        const floatx4* ofr[2][2] = { {&o00,&o01}, {&o10,&o11} };
        #pragma unroll
        for (int nt = 0; nt < 2; nt++) {
            #pragma unroll
            for (int et = 0; et < 2; et++) {
                floatx4 ov = *ofr[nt][et];
                sm.u.xs[(w*32+nt*16+quad*4+0)*72 + 32 + et*16 + L15] = (_Float16)(ov[0]*li[nt][0]);
                sm.u.xs[(w*32+nt*16+quad*4+1)*72 + 32 + et*16 + L15] = (_Float16)(ov[1]*li[nt][1]);
                sm.u.xs[(w*32+nt*16+quad*4+2)*72 + 32 + et*16 + L15] = (_Float16)(ov[2]*li[nt][2]);
                sm.u.xs[(w*32+nt*16+quad*4+3)*72 + 32 + et*16 + L15] = (_Float16)(ov[3]*li[nt][3]);
            }
        }
    }

    // ---- MLP weight A-frags: A[m=o=mt*16+L15][k=i=quad*4+j] ----
    half4 a1f[2][4], a2f[2][2], a3f[2][2];
    #pragma unroll
    for (int mt = 0; mt < 2; mt++) {
        #pragma unroll
        for (int kt = 0; kt < 4; kt++) {
            float4 f = *(const float4*)(w_h1 + (size_t)(g*32+mt*16+L15)*64 + kt*16 + quad*4);
            half2 ha = pkcvt(f.x, f.y);
            half2 hb = pkcvt(f.z, f.w);
            half4 h = { ha[0], ha[1], hb[0], hb[1] };
            a1f[mt][kt] = h;
        }
        #pragma unroll
        for (int kt = 0; kt < 2; kt++) {
            float4 f = *(const float4*)(w_h10 + (size_t)(g*32+mt*16+L15)*32 + kt*16 + quad*4);
            half2 ha = pkcvt(f.x, f.y);
            half2 hb = pkcvt(f.z, f.w);
            half4 h = { ha[0], ha[1], hb[0], hb[1] };
            a2f[mt][kt] = h;
            float4 f2 = *(const float4*)(w_h11 + (size_t)(g*32+mt*16+L15)*32 + kt*16 + quad*4);
            half2 hc = pkcvt(f2.x, f2.y);
            half2 hd = pkcvt(f2.z, f2.w);
            half4 h2 = { hc[0], hc[1], hd[0], hd[1] };
            a3f[mt][kt] = h2;
        }
    }

    // ---- layer 1 (bias-seeded): D[o][q] over this wave's 32 q rows ----
    floatx4 d1[2][2];
    #pragma unroll
    for (int mt = 0; mt < 2; mt++) {
        float4 bb = *(const float4*)&sm.bl1[mt*16 + quad*4];
        floatx4 seed = { bb.x, bb.y, bb.z, bb.w };
        d1[mt][0] = seed; d1[mt][1] = seed;
    }
    #pragma unroll
    for (int nt = 0; nt < 2; nt++)
        #pragma unroll
        for (int kt = 0; kt < 4; kt++) {
            half4 b1 = *(const half4*)&sm.u.xs[(w*32+nt*16+L15)*72 + kt*16 + quad*4];
            d1[0][nt] = MFMA16(a1f[0][kt], b1, d1[0][nt], 0,0,0);
            d1[1][nt] = MFMA16(a1f[1][kt], b1, d1[1][nt], 0,0,0);
        }
    half4 h1b[2][2];   // C layout == next layer's B layout: in-register chain
    #pragma unroll
    for (int mt = 0; mt < 2; mt++)
        #pragma unroll
        for (int nt = 0; nt < 2; nt++) {
            float v0 = d1[mt][nt][0]; v0 = (v0>=0.f)?v0:NEG*v0;
            float v1 = d1[mt][nt][1]; v1 = (v1>=0.f)?v1:NEG*v1;
            float v2 = d1[mt][nt][2]; v2 = (v2>=0.f)?v2:NEG*v2;
            float v3 = d1[mt][nt][3]; v3 = (v3>=0.f)?v3:NEG*v3;
            half2 ha = pkcvt(v0, v1);
            half2 hb = pkcvt(v2, v3);
            half4 h = { ha[0], ha[1], hb[0], hb[1] };
            h1b[mt][nt] = h;
        }
    floatx4 d2[2][2];
    #pragma unroll
    for (int mt = 0; mt < 2; mt++) {
        float4 bb = *(const float4*)&sm.bl10[mt*16 + quad*4];
        floatx4 seed = { bb.x, bb.y, bb.z, bb.w };
        d2[mt][0] = seed; d2[mt][1] = seed;
    }
    #pragma unroll
    for (int mt = 0; mt < 2; mt++)
        #pragma unroll
        for (int nt = 0; nt < 2; nt++)
            #pragma unroll
            for (int kt = 0; kt < 2; kt++)
                d2[mt][nt] = MFMA16(a2f[mt][kt], h1b[kt][nt], d2[mt][nt], 0,0,0);
    half4 h2b[2][2];
    #pragma unroll
    for (int mt = 0; mt < 2; mt++)
        #pragma unroll
        for (int nt = 0; nt < 2; nt++) {
            float v0 = d2[mt][nt][0]; v0 = (v0>=0.f)?v0:NEG*v0;
            float v1 = d2[mt][nt][1]; v1 = (v1>=0.f)?v1:NEG*v1;
            float v2 = d2[mt][nt][2]; v2 = (v2>=0.f)?v2:NEG*v2;
            float v3 = d2[mt][nt][3]; v3 = (v3>=0.f)?v3:NEG*v3;
            half2 ha = pkcvt(v0, v1);
            half2 hb = pkcvt(v2, v3);
            half4 h = { ha[0], ha[1], hb[0], hb[1] };
            h2b[mt][nt] = h;
        }
    floatx4 d3[2][2];
    #pragma unroll
    for (int mt = 0; mt < 2; mt++) {
        float4 bb = *(const float4*)&sm.bl11[mt*16 + quad*4];
        floatx4 seed = { bb.x, bb.y, bb.z, bb.w };
        d3[mt][0] = seed; d3[mt][1] = seed;
    }
    #pragma unroll
    for (int mt = 0; mt < 2; mt++)
        #pragma unroll
        for (int nt = 0; nt < 2; nt++)
            #pragma unroll
            for (int kt = 0; kt < 2; kt++)
                d3[mt][nt] = MFMA16(a3f[mt][kt], h2b[kt][nt], d3[mt][nt], 0,0,0);
    // store: lane holds out[q=qbase+w*32+nt*16+L15][o=mt*16+quad*4+r] -> float4
    #pragma unroll
    for (int mt = 0; mt < 2; mt++)
        #pragma unroll
        for (int nt = 0; nt < 2; nt++) {
            float4 ov;
            ov.x = d3[mt][nt][0]; ov.x = (ov.x>=0.f)?ov.x:NEG*ov.x;
            ov.y = d3[mt][nt][1]; ov.y = (ov.y>=0.f)?ov.y:NEG*ov.y;
            ov.z = d3[mt][nt][2]; ov.z = (ov.z>=0.f)?ov.z:NEG*ov.z;
            ov.w = d3[mt][nt][3]; ov.w = (ov.w>=0.f)?ov.w:NEG*ov.w;
            *(float4*)(out + ((size_t)b*N_ + qbase + w*32 + nt*16 + L15)*64 + g*32 + mt*16 + quad*4) = ov;
        }
}

extern "C" void kernel_launch(void* const* d_in, const int* in_sizes, int n_in,
                              void* d_out, int out_size, void* d_ws, size_t ws_size,
                              hipStream_t stream) {
    const float* x_e   = (const float*)d_in[0];
    const float* w_qkv = (const float*)d_in[1];
    const float* b_qkv = (const float*)d_in[2];
    const float* w_h1  = (const float*)d_in[3];
    const float* b_h1  = (const float*)d_in[4];
    const float* w_h10 = (const float*)d_in[5];
    const float* b_h10 = (const float*)d_in[6];
    const float* w_h11 = (const float*)d_in[7];
    const float* b_h11 = (const float*)d_in[8];
    float* out = (float*)d_out;

    hipLaunchKernelGGL(fused_kernel, dim3(B_*2*8), dim3(256), 0, stream,
                       x_e, w_qkv, b_qkv, w_h1, b_h1, w_h10, b_h10, w_h11, b_h11, out);
}